// Round 5
// baseline (24.404 us; speedup 1.0000x reference)
//
#include <hip/hip_runtime.h>

#define BS 1024
#define D_IN 512
#define D_OUT 512
#define N_MASKS 8
#define CB 16            // output cols per block

typedef short bf16x8 __attribute__((ext_vector_type(8)));
typedef float f32x4 __attribute__((ext_vector_type(4)));

// ws (int units): wsi[0..8] group offsets; wsi[16+p] row perm, p in [0,1024)

__device__ __forceinline__ ushort f2bf(float f) {
    union { float f; unsigned u; } x; x.f = f;
    unsigned r = (x.u + 0x7fffu + ((x.u >> 16) & 1u)) >> 16;  // RNE
    return (ushort)r;
}

__device__ __forceinline__ bf16x8 pack8(float4 a0, float4 a1) {
    union { uint u[4]; bf16x8 v; } r;
    r.u[0] = (uint)f2bf(a0.x) | ((uint)f2bf(a0.y) << 16);
    r.u[1] = (uint)f2bf(a0.z) | ((uint)f2bf(a0.w) << 16);
    r.u[2] = (uint)f2bf(a1.x) | ((uint)f2bf(a1.y) << 16);
    r.u[3] = (uint)f2bf(a1.z) | ((uint)f2bf(a1.w) << 16);
    return r.v;
}

// ---------------- Kernel A: counting sort of rows by state ----------------
__global__ void __launch_bounds__(BS) sort_kernel(const int* __restrict__ state,
                                                  int* __restrict__ wsi) {
    __shared__ int cnt[N_MASKS];
    __shared__ int offs[N_MASKS + 1];
    const int tid = threadIdx.x;
    if (tid < N_MASKS) cnt[tid] = 0;
    __syncthreads();
    const int s = state[tid];
    atomicAdd(&cnt[s], 1);
    __syncthreads();
    if (tid == 0) {
        int acc = 0;
        for (int i = 0; i < N_MASKS; ++i) { offs[i] = acc; acc += cnt[i]; }
        offs[N_MASKS] = acc;
    }
    __syncthreads();
    if (tid <= N_MASKS) wsi[tid] = offs[tid];
    if (tid < N_MASKS) cnt[tid] = offs[tid];   // scatter cursors
    __syncthreads();
    const int pos = atomicAdd(&cnt[s], 1);
    wsi[16 + pos] = tid;
}

// ---------------- Fused: stage W-slice in LDS (bf16 frag layout) + MFMA ----------------
// grid = (mask n fastest -> XCD colocation, colblock of 16). 512 threads = 8 waves.
// LDS layout (r2-verified): slot = kb*64 + lane; lane=(g,cl) holds
// B[k = kb*32 + g*8 + j][col = cb0 + cl], j=0..7, consecutive k pairs per dword.
__global__ void __launch_bounds__(512) fused_kernel(
    const float* __restrict__ x, const float* __restrict__ kern,
    const float* __restrict__ masks, const int* __restrict__ wsi,
    float* __restrict__ out)
{
    __shared__ ushort wlds[16 * 64 * 8];   // 16 KB
    const int n   = blockIdx.x;
    const int cb0 = blockIdx.y * CB;
    const int tid = threadIdx.x;
    const float* __restrict__ maskn = masks + (size_t)n * (D_IN * D_OUT);

    // ---- stage kern*mask -> bf16 fragment-linear LDS (2 slots/thread) ----
    #pragma unroll
    for (int it = 0; it < 2; ++it) {
        const int slot = it * 512 + tid;       // [0,1024)
        const int kb = slot >> 6;
        const int l  = slot & 63;
        const int g  = l >> 4;
        const int cl = l & 15;
        const int kbase = kb * 32 + g * 8;
        const float* kp = kern  + (size_t)kbase * D_OUT + cb0 + cl;
        const float* mp = maskn + (size_t)kbase * D_OUT + cb0 + cl;
        uint pk[4];
        #pragma unroll
        for (int h = 0; h < 4; ++h) {
            const float v0 = kp[(2*h)   * D_OUT] * mp[(2*h)   * D_OUT];
            const float v1 = kp[(2*h+1) * D_OUT] * mp[(2*h+1) * D_OUT];
            pk[h] = (uint)f2bf(v0) | ((uint)f2bf(v1) << 16);
        }
        uint4 o; o.x = pk[0]; o.y = pk[1]; o.z = pk[2]; o.w = pk[3];
        *(uint4*)&wlds[slot * 8] = o;
    }
    __syncthreads();

    // ---- per-wave rowtiles ----
    const int off0 = wsi[n];
    const int off1 = wsi[n + 1];
    const int gcnt = off1 - off0;
    const int lane = tid & 63;
    const int wid  = tid >> 6;
    const int g    = lane >> 4;
    const int cl   = lane & 15;

    for (int rt = wid; rt * 16 < gcnt; rt += 8) {
        const int p  = off0 + rt * 16 + cl;
        const int rv = (p < off1) ? wsi[16 + p] : -1;   // A row for this lane (col cl)
        const float* xr = x + (size_t)(rv < 0 ? 0 : rv) * D_IN + g * 8;

        f32x4 acc = {0.f, 0.f, 0.f, 0.f};
        #pragma unroll
        for (int kb = 0; kb < 16; ++kb) {
            const float4 a0 = *(const float4*)(xr + kb * 32);
            const float4 a1 = *(const float4*)(xr + kb * 32 + 4);
            const bf16x8 a  = pack8(a0, a1);
            const bf16x8 b  = *(const bf16x8*)&wlds[(kb * 64 + lane) * 8];
            acc = __builtin_amdgcn_mfma_f32_16x16x32_bf16(a, b, acc, 0, 0, 0);
        }

        // C/D: col = cl, row-in-tile = g*4 + r
        #pragma unroll
        for (int r = 0; r < 4; ++r) {
            const int brow = __shfl(rv, g * 4 + r);   // lanes 0..15 hold rows 0..15
            if (brow >= 0) {
                out[(size_t)brow * D_OUT + cb0 + cl] = fmaxf(acc[r], 0.f);
            }
        }
    }
}

extern "C" void kernel_launch(void* const* d_in, const int* in_sizes, int n_in,
                              void* d_out, int out_size, void* d_ws, size_t ws_size,
                              hipStream_t stream) {
    const float* x     = (const float*)d_in[0];
    const int*   state = (const int*)d_in[1];
    const float* kern  = (const float*)d_in[2];
    const float* masks = (const float*)d_in[3];
    float* out = (float*)d_out;
    int*   wsi = (int*)d_ws;

    sort_kernel<<<1, BS, 0, stream>>>(state, wsi);
    dim3 grid(N_MASKS, D_OUT / CB);
    fused_kernel<<<grid, 512, 0, stream>>>(x, kern, masks, wsi, out);
}

// Round 6
// 15.890 us; speedup vs baseline: 1.5359x; 1.5359x over previous
//
#include <hip/hip_runtime.h>

#define BS 1024
#define D_IN 512
#define D_OUT 512
#define N_MASKS 8

typedef short bf16x8 __attribute__((ext_vector_type(8)));
typedef float f32x4 __attribute__((ext_vector_type(4)));

// ws layout (bytes):
//   [0,    64)      int group offsets wsi[0..8]
//   [64,   4224)    int row-perm wsi[16 + p], p in [0,1024)
//   [8192, +4MB)    Wf: 8 masks x 16 kb x 32 cb x 1024B fragment blocks
//   [XB_OFF, +1MB)  xb: 1024 x 512 bf16
#define WF_OFF_USH (8192 / 2)
#define WF_USH     (N_MASKS * 16 * 32 * 512)
#define XB_OFF_USH (WF_OFF_USH + WF_USH)

__device__ __forceinline__ ushort f2bf(float f) {
    union { float f; unsigned u; } x; x.f = f;
    unsigned r = (x.u + 0x7fffu + ((x.u >> 16) & 1u)) >> 16;  // RNE
    return (ushort)r;
}

// ---------------- Prepass (byte-identical to round 2) ----------------
__global__ void __launch_bounds__(256) prep_kernel(
    const float* __restrict__ x, const int* __restrict__ state,
    const float* __restrict__ kern, const float* __restrict__ masks,
    int* __restrict__ wsi, ushort* __restrict__ wf, ushort* __restrict__ xb)
{
    const int bx  = blockIdx.x;
    const int tid = threadIdx.x;

    if (bx < 1024) {
        const int n  = bx >> 7;
        const int kb = (bx >> 3) & 15;
        const int cb = (bx & 7) * 4 + (tid >> 6);
        const int l  = tid & 63;
        const int g  = l >> 4;
        const int cl = l & 15;
        const int k0  = kb * 32 + g * 8;
        const int col = cb * 16 + cl;
        const float* kp = kern + (size_t)k0 * D_OUT + col;
        const float* mp = masks + (size_t)n * (D_IN * D_OUT) + (size_t)k0 * D_OUT + col;
        uint pk[4];
        #pragma unroll
        for (int j = 0; j < 4; ++j) {
            float v0 = kp[(2*j)   * D_OUT] * mp[(2*j)   * D_OUT];
            float v1 = kp[(2*j+1) * D_OUT] * mp[(2*j+1) * D_OUT];
            pk[j] = (uint)f2bf(v0) | ((uint)f2bf(v1) << 16);
        }
        uint4 o; o.x = pk[0]; o.y = pk[1]; o.z = pk[2]; o.w = pk[3];
        *(uint4*)(wf + ((size_t)((n * 16 + kb) * 32 + cb)) * 512 + l * 8) = o;
    } else if (bx < 1280) {
        const int idx = (bx - 1024) * 256 + tid;        // [0, 65536)
        const float4 a = ((const float4*)x)[idx * 2];
        const float4 b = ((const float4*)x)[idx * 2 + 1];
        uint4 o;
        o.x = (uint)f2bf(a.x) | ((uint)f2bf(a.y) << 16);
        o.y = (uint)f2bf(a.z) | ((uint)f2bf(a.w) << 16);
        o.z = (uint)f2bf(b.x) | ((uint)f2bf(b.y) << 16);
        o.w = (uint)f2bf(b.z) | ((uint)f2bf(b.w) << 16);
        *(uint4*)(xb + (size_t)idx * 8) = o;
    } else {
        __shared__ int cnt[N_MASKS];
        __shared__ int offs[N_MASKS + 1];
        if (tid < N_MASKS) cnt[tid] = 0;
        __syncthreads();
        int s[4];
        #pragma unroll
        for (int r = 0; r < 4; ++r) {
            s[r] = state[r * 256 + tid];
            atomicAdd(&cnt[s[r]], 1);
        }
        __syncthreads();
        if (tid == 0) {
            int acc = 0;
            for (int i = 0; i < N_MASKS; ++i) { offs[i] = acc; acc += cnt[i]; }
            offs[N_MASKS] = acc;
        }
        __syncthreads();
        if (tid <= N_MASKS) wsi[tid] = offs[tid];
        if (tid < N_MASKS) cnt[tid] = offs[tid];
        __syncthreads();
        #pragma unroll
        for (int r = 0; r < 4; ++r) {
            const int pos = atomicAdd(&cnt[s[r]], 1);
            wsi[16 + pos] = r * 256 + tid;
        }
    }
}

// ---------------- GEMM v6: K split 4-ways across the block's 4 waves ----------------
// grid = (mask n fastest -> XCD colocation, 16 col-groups of 32, 8 rowtile bases)
// 1024 blocks ALL active (rowtile loop), 4 waves/SIMD. Wave w: K-quarter partial
// (4 a-loads, 8 contiguous 1KB b-loads, 8 MFMA) -> LDS reduce -> wave 0 stores.
__global__ void __launch_bounds__(256, 4) gemm_kernel(
    const ushort* __restrict__ xb, const ushort* __restrict__ wf,
    const int* __restrict__ wsi, float* __restrict__ out)
{
    const int n   = blockIdx.x;
    const int cb0 = blockIdx.y * 2;          // two 16-col fragments
    const int off0 = wsi[n];
    const int off1 = wsi[n + 1];
    const int gcnt = off1 - off0;

    const int tid  = threadIdx.x;
    const int lane = tid & 63;
    const int wid  = tid >> 6;               // K-quarter id
    const int g    = lane >> 4;
    const int cl   = lane & 15;

    __shared__ float red[3][2][64][4];       // partials from waves 1..3 (6 KB)

    // Wf (r2 layout): ((n*16 + kb)*32 + cb)*512 + lane*8 ; this wave starts at kb = wid*4
    const ushort* wp0 = wf + ((size_t)((n * 16 + wid * 4) * 32 + cb0)) * 512 + lane * 8;

    for (int rt = blockIdx.z; rt * 16 < gcnt; rt += 8) {
        const int p  = off0 + rt * 16 + cl;
        const int rv = (p < off1) ? wsi[16 + p] : -1;   // row at tile-position cl
        const ushort* xr = xb + (size_t)(rv < 0 ? 0 : rv) * D_IN + wid * 4 * 32 + g * 8;

        f32x4 acc0 = {0.f, 0.f, 0.f, 0.f};
        f32x4 acc1 = {0.f, 0.f, 0.f, 0.f};
        #pragma unroll
        for (int i = 0; i < 4; ++i) {        // kb = wid*4 + i
            const bf16x8 a  = *(const bf16x8*)(xr + i * 32);
            const bf16x8 b0 = *(const bf16x8*)(wp0 + (size_t)i * 32 * 512);
            const bf16x8 b1 = *(const bf16x8*)(wp0 + (size_t)i * 32 * 512 + 512);
            acc0 = __builtin_amdgcn_mfma_f32_16x16x32_bf16(a, b0, acc0, 0, 0, 0);
            acc1 = __builtin_amdgcn_mfma_f32_16x16x32_bf16(a, b1, acc1, 0, 0, 0);
        }

        if (wid) {
            *(f32x4*)&red[wid - 1][0][lane][0] = acc0;
            *(f32x4*)&red[wid - 1][1][lane][0] = acc1;
        }
        __syncthreads();
        if (wid == 0) {
            #pragma unroll
            for (int w = 0; w < 3; ++w) {
                acc0 += *(const f32x4*)&red[w][0][lane][0];
                acc1 += *(const f32x4*)&red[w][1][lane][0];
            }
            // C/D: col = cl, row-in-tile = g*4 + r
            #pragma unroll
            for (int r = 0; r < 4; ++r) {
                const int brow = __shfl(rv, g * 4 + r);
                if (brow >= 0) {
                    float* op = out + (size_t)brow * D_OUT;
                    op[cb0 * 16 + cl]       = fmaxf(acc0[r], 0.f);
                    op[(cb0 + 1) * 16 + cl] = fmaxf(acc1[r], 0.f);
                }
            }
        }
        __syncthreads();   // protect red before next iteration
    }
}

extern "C" void kernel_launch(void* const* d_in, const int* in_sizes, int n_in,
                              void* d_out, int out_size, void* d_ws, size_t ws_size,
                              hipStream_t stream) {
    const float* x     = (const float*)d_in[0];
    const int*   state = (const int*)d_in[1];
    const float* kern  = (const float*)d_in[2];
    const float* masks = (const float*)d_in[3];
    float*  out = (float*)d_out;
    int*    wsi = (int*)d_ws;
    ushort* wsu = (ushort*)d_ws;

    prep_kernel<<<1281, 256, 0, stream>>>(x, state, kern, masks,
                                          wsi, wsu + WF_OFF_USH, wsu + XB_OFF_USH);
    dim3 grid(N_MASKS, 16, 8);
    gemm_kernel<<<grid, 256, 0, stream>>>(wsu + XB_OFF_USH, wsu + WF_OFF_USH, wsi, out);
}

// Round 7
// 15.448 us; speedup vs baseline: 1.5798x; 1.0286x over previous
//
#include <hip/hip_runtime.h>

#define BS 1024
#define D_IN 512
#define D_OUT 512
#define N_MASKS 8

typedef short bf16x8 __attribute__((ext_vector_type(8)));
typedef float f32x4 __attribute__((ext_vector_type(4)));

// ws layout (bytes):
//   [0,    64)      int group offsets wsi[0..8]
//   [64,   4224)    int row-perm wsi[16 + p], p in [0,1024)
//   [8192, +4MB)    Wf: 8 masks x 16 kb x 32 cb x 1024B fragment blocks (r2 layout)
//   [XB_OFF, +1MB)  xb: 1024 x 512 bf16
#define WF_OFF_USH (8192 / 2)
#define WF_USH     (N_MASKS * 16 * 32 * 512)
#define XB_OFF_USH (WF_OFF_USH + WF_USH)

__device__ __forceinline__ ushort f2bf(float f) {
    union { float f; unsigned u; } x; x.f = f;
    unsigned r = (x.u + 0x7fffu + ((x.u >> 16) & 1u)) >> 16;  // RNE
    return (ushort)r;
}

// ---------------- Prepass v7: vectorized Wf pack via LDS transpose ----------------
// blocks [0,512): Wf pack (n, kb, 128-col tile) -> r2 fragment-linear layout
// blocks [512,768): x->bf16.  768: counting sort.
__global__ void __launch_bounds__(256) prep_kernel(
    const float* __restrict__ x, const int* __restrict__ state,
    const float* __restrict__ kern, const float* __restrict__ masks,
    int* __restrict__ wsi, ushort* __restrict__ wf, ushort* __restrict__ xb)
{
    __shared__ float prod[32][133];   // 133: odd-ish pad, phase-2 q-lanes bank-spread
    const int bx  = blockIdx.x;
    const int tid = threadIdx.x;

    if (bx < 512) {
        const int n  = bx >> 6;          // mask
        const int kb = (bx >> 2) & 15;   // 32-row k tile
        const int cg = bx & 3;           // 128-col tile
        const int k0 = kb * 32, c0 = cg * 128;
        const float* maskn = masks + (size_t)n * (D_IN * D_OUT);

        // Phase 1: coalesced float4 loads, product -> LDS
        #pragma unroll
        for (int it = 0; it < 4; ++it) {
            const int i  = it * 256 + tid;      // [0,1024)
            const int r  = i >> 5;              // 0..31
            const int c4 = i & 31;              // 0..31 (x4 cols)
            const size_t gidx = (size_t)(k0 + r) * D_OUT + c0 + c4 * 4;
            const float4 kv = *(const float4*)&kern[gidx];
            const float4 mv = *(const float4*)&maskn[gidx];
            float* dst = &prod[r][c4 * 4];
            dst[0] = kv.x * mv.x; dst[1] = kv.y * mv.y;
            dst[2] = kv.z * mv.z; dst[3] = kv.w * mv.w;
        }
        __syncthreads();

        // Phase 2: transpose-pack 8 k's of one col -> one 16B store into
        // r2 fragment layout: ((n*16+kb)*32 + cb)*512 + (g*16+cl)*8
        #pragma unroll
        for (int it = 0; it < 2; ++it) {
            const int c = it * 64 + (tid >> 2); // local col 0..127
            const int q = tid & 3;              // k subgroup g
            uint pk[4];
            #pragma unroll
            for (int h = 0; h < 4; ++h) {
                const float v0 = prod[q * 8 + 2 * h][c];
                const float v1 = prod[q * 8 + 2 * h + 1][c];
                pk[h] = (uint)f2bf(v0) | ((uint)f2bf(v1) << 16);
            }
            uint4 o; o.x = pk[0]; o.y = pk[1]; o.z = pk[2]; o.w = pk[3];
            const int cb = cg * 8 + (c >> 4);
            const int l  = q * 16 + (c & 15);
            *(uint4*)(wf + ((size_t)((n * 16 + kb) * 32 + cb)) * 512 + l * 8) = o;
        }
    } else if (bx < 768) {
        const int idx = (bx - 512) * 256 + tid;        // [0, 65536)
        const float4 a = ((const float4*)x)[idx * 2];
        const float4 b = ((const float4*)x)[idx * 2 + 1];
        uint4 o;
        o.x = (uint)f2bf(a.x) | ((uint)f2bf(a.y) << 16);
        o.y = (uint)f2bf(a.z) | ((uint)f2bf(a.w) << 16);
        o.z = (uint)f2bf(b.x) | ((uint)f2bf(b.y) << 16);
        o.w = (uint)f2bf(b.z) | ((uint)f2bf(b.w) << 16);
        *(uint4*)(xb + (size_t)idx * 8) = o;
    } else {
        __shared__ int cnt[N_MASKS];
        __shared__ int offs[N_MASKS + 1];
        if (tid < N_MASKS) cnt[tid] = 0;
        __syncthreads();
        int s[4];
        #pragma unroll
        for (int r = 0; r < 4; ++r) {
            s[r] = state[r * 256 + tid];
            atomicAdd(&cnt[s[r]], 1);
        }
        __syncthreads();
        if (tid == 0) {
            int acc = 0;
            for (int i = 0; i < N_MASKS; ++i) { offs[i] = acc; acc += cnt[i]; }
            offs[N_MASKS] = acc;
        }
        __syncthreads();
        if (tid <= N_MASKS) wsi[tid] = offs[tid];
        if (tid < N_MASKS) cnt[tid] = offs[tid];
        __syncthreads();
        #pragma unroll
        for (int r = 0; r < 4; ++r) {
            const int pos = atomicAdd(&cnt[s[r]], 1);
            wsi[16 + pos] = r * 256 + tid;
        }
    }
}

// ---------------- GEMM v6 (byte-identical to round 6) ----------------
__global__ void __launch_bounds__(256, 4) gemm_kernel(
    const ushort* __restrict__ xb, const ushort* __restrict__ wf,
    const int* __restrict__ wsi, float* __restrict__ out)
{
    const int n   = blockIdx.x;
    const int cb0 = blockIdx.y * 2;          // two 16-col fragments
    const int off0 = wsi[n];
    const int off1 = wsi[n + 1];
    const int gcnt = off1 - off0;

    const int tid  = threadIdx.x;
    const int lane = tid & 63;
    const int wid  = tid >> 6;               // K-quarter id
    const int g    = lane >> 4;
    const int cl   = lane & 15;

    __shared__ float red[3][2][64][4];       // partials from waves 1..3 (6 KB)

    const ushort* wp0 = wf + ((size_t)((n * 16 + wid * 4) * 32 + cb0)) * 512 + lane * 8;

    for (int rt = blockIdx.z; rt * 16 < gcnt; rt += 8) {
        const int p  = off0 + rt * 16 + cl;
        const int rv = (p < off1) ? wsi[16 + p] : -1;   // row at tile-position cl
        const ushort* xr = xb + (size_t)(rv < 0 ? 0 : rv) * D_IN + wid * 4 * 32 + g * 8;

        f32x4 acc0 = {0.f, 0.f, 0.f, 0.f};
        f32x4 acc1 = {0.f, 0.f, 0.f, 0.f};
        #pragma unroll
        for (int i = 0; i < 4; ++i) {        // kb = wid*4 + i
            const bf16x8 a  = *(const bf16x8*)(xr + i * 32);
            const bf16x8 b0 = *(const bf16x8*)(wp0 + (size_t)i * 32 * 512);
            const bf16x8 b1 = *(const bf16x8*)(wp0 + (size_t)i * 32 * 512 + 512);
            acc0 = __builtin_amdgcn_mfma_f32_16x16x32_bf16(a, b0, acc0, 0, 0, 0);
            acc1 = __builtin_amdgcn_mfma_f32_16x16x32_bf16(a, b1, acc1, 0, 0, 0);
        }

        if (wid) {
            *(f32x4*)&red[wid - 1][0][lane][0] = acc0;
            *(f32x4*)&red[wid - 1][1][lane][0] = acc1;
        }
        __syncthreads();
        if (wid == 0) {
            #pragma unroll
            for (int w = 0; w < 3; ++w) {
                acc0 += *(const f32x4*)&red[w][0][lane][0];
                acc1 += *(const f32x4*)&red[w][1][lane][0];
            }
            #pragma unroll
            for (int r = 0; r < 4; ++r) {
                const int brow = __shfl(rv, g * 4 + r);
                if (brow >= 0) {
                    float* op = out + (size_t)brow * D_OUT;
                    op[cb0 * 16 + cl]       = fmaxf(acc0[r], 0.f);
                    op[(cb0 + 1) * 16 + cl] = fmaxf(acc1[r], 0.f);
                }
            }
        }
        __syncthreads();   // protect red before next iteration
    }
}

extern "C" void kernel_launch(void* const* d_in, const int* in_sizes, int n_in,
                              void* d_out, int out_size, void* d_ws, size_t ws_size,
                              hipStream_t stream) {
    const float* x     = (const float*)d_in[0];
    const int*   state = (const int*)d_in[1];
    const float* kern  = (const float*)d_in[2];
    const float* masks = (const float*)d_in[3];
    float*  out = (float*)d_out;
    int*    wsi = (int*)d_ws;
    ushort* wsu = (ushort*)d_ws;

    prep_kernel<<<769, 256, 0, stream>>>(x, state, kern, masks,
                                         wsi, wsu + WF_OFF_USH, wsu + XB_OFF_USH);
    dim3 grid(N_MASKS, 16, 8);
    gemm_kernel<<<grid, 256, 0, stream>>>(wsu + XB_OFF_USH, wsu + WF_OFF_USH, wsi, out);
}